// Round 3
// baseline (183.643 us; speedup 1.0000x reference)
//
#include <hip/hip_runtime.h>
#include <hip/hip_bf16.h>
#include <hip/hip_fp16.h>

// GIN via linearity: agg(x)@W == agg(x@W). Per layer: z = X@W (MFMA fp16,
// fp32 accum), then h = relu(z + gather_sum(z) + b) via on-device CSR.
// CSR: single-pass fixed-capacity fine buckets (dst>>7, CAP2 slots each),
// packed 4B staging (src:16 | dst&127:16), LDS-local per-bucket finalize.
// r9:  finalize||GEMM1 fused; layer-2 gather pools directly into sums.
// r10: gather1+relu+GEMM2 fused (h rows via LDS tile, no hbuf round-trip).
// r11: re-paired overlap: scatter||GEMM1 fused (scatter was the serial,
//      underutilized stage; GEMM1 is CSR-independent), CHUNK 4096->1024
//      (782 scatter blocks, LDS hist contention 21-way -> 2.6-way),
//      finalize finer (391 blocks of 128 nodes, 12.8KB LDS, ~2 blk/CU),
//      col stored as u16 (halves index traffic).

#define N_FEAT 64
#define CHUNK 1024
#define BSH 7
#define BNODES 128          // 1 << BSH
#define NBKT_MAX 400
#define CAP2 2816           // slots/bucket (mean 2048, ~17 sigma slack)

typedef _Float16 f16;
typedef _Float16 half8 __attribute__((ext_vector_type(8)));
typedef float float4v __attribute__((ext_vector_type(4)));
typedef unsigned short u16;

__device__ inline f16 cvt_f16(float v) { return (f16)v; }
__device__ inline f16 cvt_f16(f16 v) { return v; }

// ---- GEMM body via MFMA: 64 rows/block, 4 waves; wave w = 16-row strip ----
// smem: needs 2*64*72*2 = 18432 bytes
template <typename TIN>
__device__ __forceinline__ void gemm_body(const TIN* __restrict__ X, const float* __restrict__ W,
                                          f16* __restrict__ Z, int nrows, int bidx, char* smemc) {
    f16 (*sX)[72] = (f16 (*)[72])smemc;
    f16 (*sWT)[72] = (f16 (*)[72])(smemc + 64 * 72 * sizeof(f16));
    int t = threadIdx.x;
    int base = bidx * 64;
    for (int idx = t; idx < 4096; idx += 256) {
        int k = idx >> 6, n = idx & 63;
        sWT[n][k] = (f16)W[idx];               // W[k][n] -> sWT[n][k]
    }
    for (int idx = t; idx < 4096; idx += 256) {
        int r = idx >> 6, c = idx & 63;
        int row = base + r;
        sX[r][c] = (row < nrows) ? cvt_f16(X[(size_t)row * 64 + c]) : (f16)0.f;
    }
    __syncthreads();
    int wave = t >> 6;
    int lane = t & 63;
    int quad = lane >> 4;
    int m16 = lane & 15;
    half8 a0 = *(const half8*)&sX[wave * 16 + m16][quad * 8];
    half8 a1 = *(const half8*)&sX[wave * 16 + m16][32 + quad * 8];
    float4v acc[4];
#pragma unroll
    for (int C = 0; C < 4; ++C) {
        half8 b0 = *(const half8*)&sWT[C * 16 + m16][quad * 8];
        half8 b1 = *(const half8*)&sWT[C * 16 + m16][32 + quad * 8];
        float4v d = {0.f, 0.f, 0.f, 0.f};
        d = __builtin_amdgcn_mfma_f32_16x16x32_f16(a0, b0, d, 0, 0, 0);
        d = __builtin_amdgcn_mfma_f32_16x16x32_f16(a1, b1, d, 0, 0, 0);
        acc[C] = d;
    }
#pragma unroll
    for (int reg = 0; reg < 4; ++reg) {
        int row = base + wave * 16 + quad * 4 + reg;
        if (row < nrows) {
#pragma unroll
            for (int C = 0; C < 4; ++C)
                Z[(size_t)row * 64 + C * 16 + m16] = (f16)acc[C][reg];
        }
    }
}

// ---- CSR pass A body: fine-bucket packed edges into fixed-capacity regions ----
// pack = src(16b) | (dst&127)<<16    (requires N <= 65536)
// smem: (CHUNK*2 + NBKT_MAX*2) * 4 = 11392 bytes
__device__ __forceinline__ void scatter_body(const int* __restrict__ src, const int* __restrict__ dst,
                                             int* __restrict__ ccur, int* __restrict__ staging,
                                             int E, int nbkt, int bidx, char* smemc) {
    int* epack = (int*)smemc;           // CHUNK
    int* ebkt  = epack + CHUNK;         // CHUNK
    int* hist  = ebkt + CHUNK;          // NBKT_MAX
    int* base  = hist + NBKT_MAX;       // NBKT_MAX
    int t = threadIdx.x;
    int begin = bidx * CHUNK;
    int cnt = min(CHUNK, E - begin);
    for (int i = t; i < nbkt; i += 256) hist[i] = 0;
    __syncthreads();
    for (int i = t; i < cnt; i += 256) {
        int d = dst[begin + i];
        int s = src[begin + i];
        epack[i] = (s & 0xFFFF) | ((d & (BNODES - 1)) << 16);
        ebkt[i] = d >> BSH;
        atomicAdd(&hist[d >> BSH], 1);
    }
    __syncthreads();
    for (int i = t; i < nbkt; i += 256) {
        int h = hist[i];
        if (h > 0) base[i] = atomicAdd(&ccur[i], h);
        hist[i] = 0;
    }
    __syncthreads();
    for (int i = t; i < cnt; i += 256) {
        int b = ebkt[i];
        int off = base[b] + atomicAdd(&hist[b], 1);
        if (off < CAP2) staging[(size_t)b * CAP2 + off] = epack[i];
    }
}

// ---- fused: scatter (blocks 0..nsb-1) || layer-1 GEMM (blocks nsb..) ----
// independent: scatter reads src/dst writes staging/ccur; gemm reads X/W1
// writes Z1. GEMM blocks backfill; scatter no longer a serial stage.
__global__ __launch_bounds__(256) void fused_scatter_gemm(
        const int* __restrict__ src, const int* __restrict__ dst,
        int* __restrict__ ccur, int* __restrict__ staging, int E, int nbkt,
        const float* __restrict__ X, const float* __restrict__ W,
        f16* __restrict__ Z, int nrows, int nsb) {
    __shared__ __align__(16) char smem[2 * 64 * 72 * sizeof(f16)];
    if ((int)blockIdx.x < nsb)
        scatter_body(src, dst, ccur, staging, E, nbkt, blockIdx.x, smem);
    else
        gemm_body<float>(X, W, Z, nrows, blockIdx.x - nsb, smem);
}

// ---- CSR pass B: per-bucket hist+scan+scatter fully in LDS ----
// 128-node buckets: 391 blocks, smem = CAP2*4 + 3*128*4 = 12800 bytes
__global__ __launch_bounds__(256) void bucket_finalize(
        const int* __restrict__ staging, const int* __restrict__ ccur,
        int2* __restrict__ rowse, u16* __restrict__ col, int N) {
    __shared__ int edges[CAP2];
    __shared__ int hist[BNODES];
    __shared__ int scan[BNODES];
    __shared__ int cur[BNODES];
    int b = blockIdx.x, t = threadIdx.x;
    int cnt = min(ccur[b], CAP2);
    int sbase = b * CAP2;
    if (t < BNODES) hist[t] = 0;
    __syncthreads();
    for (int i = t; i < cnt; i += 256) {
        int e = staging[(size_t)sbase + i];
        edges[i] = e;
        atomicAdd(&hist[(e >> 16) & (BNODES - 1)], 1);
    }
    __syncthreads();
    int v = (t < BNODES) ? hist[t] : 0;
    if (t < BNODES) scan[t] = v;
    __syncthreads();
    for (int off = 1; off < BNODES; off <<= 1) {
        int u = (t >= off && t < BNODES) ? scan[t - off] : 0;
        __syncthreads();
        if (t < BNODES) scan[t] += u;
        __syncthreads();
    }
    if (t < BNODES) {
        int excl = scan[t] - v;
        cur[t] = excl;
        int node = b * BNODES + t;
        if (node < N) rowse[node] = make_int2(sbase + excl, sbase + excl + v);
    }
    __syncthreads();
    for (int i = t; i < cnt; i += 256) {
        int e = edges[i];
        int pos = sbase + atomicAdd(&cur[(e >> 16) & (BNODES - 1)], 1);
        col[pos] = (u16)(e & 0xFFFF);
    }
}

// ---- fused gather1 + relu + layer-2 GEMM ----
// 512 threads = 8 waves; block owns 32 nodes (wave w -> nodes w*4..w*4+3).
// Per node: 8 edge slots (e=lane>>3) x 8 chunks of 16B (c=lane&7), 32 edges
// in flight; shfl-reduce across slots; lanes e==0 write h row to sH[32][72]
// as f16. One barrier, then 8 waves compute the 32x64 z2 tile vs staged W2^T.
__global__ __launch_bounds__(512) void gather_gemm(
        const f16* __restrict__ Z, const int2* __restrict__ rowse,
        const u16* __restrict__ col, const float* __restrict__ bias,
        const float* __restrict__ W2, f16* __restrict__ Z2, int n) {
    __shared__ f16 sH[32][72];
    __shared__ f16 sWT[64][72];
    int t = threadIdx.x;
    for (int idx = t; idx < 4096; idx += 512) {
        int k = idx >> 6, nn = idx & 63;
        sWT[nn][k] = (f16)W2[idx];             // W2[k][n] -> sWT[n][k]
    }
    int w = t >> 6;
    int lane = t & 63;
    int e = lane >> 3, c = lane & 7;
    int base = blockIdx.x * 32;
    const float4v* Z4 = reinterpret_cast<const float4v*>(Z);
    const float4* B4 = reinterpret_cast<const float4*>(bias);
#pragma unroll
    for (int q = 0; q < 4; ++q) {
        int node = base + w * 4 + q;
        bool valid = node < n;
        int lo = 0, hi = 0;
        if (valid) { int2 se = rowse[node]; lo = se.x; hi = se.y; }
        float acc[8] = {0.f, 0.f, 0.f, 0.f, 0.f, 0.f, 0.f, 0.f};
        int idx4[4];
#pragma unroll
        for (int i = 0; i < 4; ++i) {
            int j = lo + e + i * 8;
            idx4[i] = (j < hi) ? (int)col[j] : -1;
        }
#pragma unroll
        for (int i = 0; i < 4; ++i) {
            if (idx4[i] >= 0) {
                float4v r = Z4[(size_t)idx4[i] * 8 + c];
                half8 hv = *(half8*)&r;
#pragma unroll
                for (int k = 0; k < 8; ++k) acc[k] += (float)hv[k];
            }
        }
        for (int j = lo + 32 + e; j < hi; j += 8) {   // rare tail (deg > 32)
            float4v r = Z4[(size_t)(int)col[j] * 8 + c];
            half8 hv = *(half8*)&r;
#pragma unroll
            for (int k = 0; k < 8; ++k) acc[k] += (float)hv[k];
        }
#pragma unroll
        for (int k = 0; k < 8; ++k) {
            acc[k] += __shfl_xor(acc[k], 8);
            acc[k] += __shfl_xor(acc[k], 16);
            acc[k] += __shfl_xor(acc[k], 32);
        }
        if (e == 0) {                          // lane == c here
            half8 o;
            if (valid) {
                float4v sr = Z4[(size_t)node * 8 + c];
                half8 sv = *(half8*)&sr;
                float4 b0 = B4[c * 2];
                float4 b1 = B4[c * 2 + 1];
                float bb[8] = {b0.x, b0.y, b0.z, b0.w, b1.x, b1.y, b1.z, b1.w};
#pragma unroll
                for (int k = 0; k < 8; ++k)
                    o[k] = (f16)fmaxf((float)sv[k] + acc[k] + bb[k], 0.f);
            } else {
#pragma unroll
                for (int k = 0; k < 8; ++k) o[k] = (f16)0.f;
            }
            *(half8*)&sH[w * 4 + q][c * 8] = o;
        }
    }
    __syncthreads();
    // ---- 32x64 MFMA: wave w -> output tile (mrow = (w>>2)*16, ncol = (w&3)*16)
    int quad = lane >> 4;
    int m16 = lane & 15;
    int mrow = (w >> 2) * 16;
    int ncol = (w & 3) * 16;
    half8 a0 = *(const half8*)&sH[mrow + m16][quad * 8];
    half8 a1 = *(const half8*)&sH[mrow + m16][32 + quad * 8];
    half8 b0 = *(const half8*)&sWT[ncol + m16][quad * 8];
    half8 b1 = *(const half8*)&sWT[ncol + m16][32 + quad * 8];
    float4v d = {0.f, 0.f, 0.f, 0.f};
    d = __builtin_amdgcn_mfma_f32_16x16x32_f16(a0, b0, d, 0, 0, 0);
    d = __builtin_amdgcn_mfma_f32_16x16x32_f16(a1, b1, d, 0, 0, 0);
#pragma unroll
    for (int reg = 0; reg < 4; ++reg) {
        int row = base + mrow + quad * 4 + reg;
        if (row < n)
            Z2[(size_t)row * 64 + ncol + m16] = (f16)d[reg];
    }
}

// ---- gather2 + bias + relu + pool; 1 wave/node ----
// Block-local LDS combine of the 4 waves' h rows, atomicAdd per distinct
// graph (batch sorted -> usually one graph per block -> ~64 atomics/block).
__global__ __launch_bounds__(256) void gather_pool(
        const f16* __restrict__ Z, const int2* __restrict__ rowse,
        const u16* __restrict__ col, const float* __restrict__ bias,
        float* __restrict__ sums, const int* __restrict__ batch, int n) {
    __shared__ float sh[4][64];
    __shared__ int gid[4];
    int w = threadIdx.x >> 6;
    int node = (int)(blockIdx.x * 4 + w);
    int lane = threadIdx.x & 63;
    int e = lane >> 3, c = lane & 7;
    bool valid = node < n;
    int lo = 0, hi = 0;
    if (valid) { int2 se = rowse[node]; lo = se.x; hi = se.y; }
    const float4v* Z4 = reinterpret_cast<const float4v*>(Z);
    float acc[8] = {0.f, 0.f, 0.f, 0.f, 0.f, 0.f, 0.f, 0.f};
    int idx[4];
#pragma unroll
    for (int i = 0; i < 4; ++i) {
        int j = lo + e + i * 8;
        idx[i] = (j < hi) ? (int)col[j] : -1;
    }
#pragma unroll
    for (int i = 0; i < 4; ++i) {
        if (idx[i] >= 0) {
            float4v r = Z4[(size_t)idx[i] * 8 + c];
            half8 hv = *(half8*)&r;
#pragma unroll
            for (int k = 0; k < 8; ++k) acc[k] += (float)hv[k];
        }
    }
    for (int j = lo + 32 + e; j < hi; j += 8) {   // rare tail (deg > 32)
        float4v r = Z4[(size_t)(int)col[j] * 8 + c];
        half8 hv = *(half8*)&r;
#pragma unroll
        for (int k = 0; k < 8; ++k) acc[k] += (float)hv[k];
    }
#pragma unroll
    for (int k = 0; k < 8; ++k) {
        acc[k] += __shfl_xor(acc[k], 8);
        acc[k] += __shfl_xor(acc[k], 16);
        acc[k] += __shfl_xor(acc[k], 32);
    }
    if (lane == 0) gid[w] = valid ? batch[node] : -1;
    if (valid && e == 0) {
        float4v sr = Z4[(size_t)node * 8 + c];
        half8 sv = *(half8*)&sr;
        const float4* B4 = reinterpret_cast<const float4*>(bias);
        float4 b0 = B4[c * 2];
        float4 b1 = B4[c * 2 + 1];
        float bb[8] = {b0.x, b0.y, b0.z, b0.w, b1.x, b1.y, b1.z, b1.w};
#pragma unroll
        for (int k = 0; k < 8; ++k)
            sh[w][c * 8 + k] = fmaxf((float)sv[k] + acc[k] + bb[k], 0.f);
    }
    __syncthreads();
    if (w == 0) {
        int cg = gid[0];
        float run = 0.f;
#pragma unroll
        for (int q = 0; q < 4; ++q) {
            int g = gid[q];
            if (g < 0) break;
            if (g != cg) {
                atomicAdd(&sums[cg * 64 + lane], run);
                run = 0.f;
                cg = g;
            }
            run += sh[q][lane];
        }
        if (cg >= 0) atomicAdd(&sums[cg * 64 + lane], run);
    }
}

// ---- tiny head: out[g] = (sums[g]/cnt[g]) @ W3 + b3 ----
__global__ __launch_bounds__(64) void head_kernel(
        const float* __restrict__ sums, const int* __restrict__ batch,
        const float* __restrict__ W3, const float* __restrict__ b3,
        float* __restrict__ out, int n, int ncls) {
    int g = blockIdx.x;
    __shared__ float row[64];
    __shared__ int bnd[2];
    int t = threadIdx.x;
    if (t < 2) {
        int target = g + t;
        int lo = 0, hi = n;
        while (lo < hi) { int m = (lo + hi) >> 1; if (batch[m] < target) lo = m + 1; else hi = m; }
        bnd[t] = lo;
    }
    __syncthreads();
    float cnt = fmaxf((float)(bnd[1] - bnd[0]), 1.0f);
    row[t] = sums[g * 64 + t] / cnt;
    __syncthreads();
    if (t < ncls) {
        float o = b3[t];
#pragma unroll
        for (int k = 0; k < 64; ++k) o += row[k] * W3[k * ncls + t];
        out[g * ncls + t] = o;
    }
}

extern "C" void kernel_launch(void* const* d_in, const int* in_sizes, int n_in,
                              void* d_out, int out_size, void* d_ws, size_t ws_size,
                              hipStream_t stream) {
    const float* x     = (const float*)d_in[0];
    const int*   ei    = (const int*)d_in[1];   // [2, E]
    const int*   batch = (const int*)d_in[2];
    const float* W1    = (const float*)d_in[3];
    const float* b1    = (const float*)d_in[4];
    const float* W2    = (const float*)d_in[5];
    const float* b2    = (const float*)d_in[6];
    const float* W3    = (const float*)d_in[7];
    const float* b3    = (const float*)d_in[8];
    float* out = (float*)d_out;

    const int N = in_sizes[0] / N_FEAT;       // 50000
    const int E = in_sizes[1] / 2;            // 800000
    const int NCLS = 10;
    const int G = out_size / NCLS;            // 500
    const int* src = ei;
    const int* dst = ei + E;
    const int nbkt = (N + BNODES - 1) / BNODES;   // 391 fine buckets

    // workspace layout (offsets kept 16B-aligned)
    int*   staging = (int*)d_ws;                              // nbkt*CAP2
    int2*  rowse   = (int2*)(staging + (size_t)nbkt * CAP2);  // N
    u16*   col     = (u16*)(rowse + N);                       // nbkt*CAP2 (2B)
    size_t colInts = ((size_t)nbkt * CAP2 * 2 + 15) / 16 * 4; // ints, 16B pad
    int*   ccur    = (int*)(rowse + N) + colInts;             // NBKT_MAX
    float* sums    = (float*)(ccur + NBKT_MAX);               // G*64 (pool acc)
    f16*   zbuf    = (f16*)(sums + (size_t)G * 64);           // N*64  (z1)
    f16*   z2buf   = zbuf + (size_t)N * 64;                   // N*64  (z2)

    const int gemmGrid = (N + 63) / 64;           // 782
    const int nsb = (E + CHUNK - 1) / CHUNK;      // 782
    const int gg2Grid  = (N + 31) / 32;
    const int gatherGrid = (N + 3) / 4;

    // ---- zero ccur + sums (contiguous) ----
    hipMemsetAsync(ccur, 0, (NBKT_MAX + (size_t)G * 64) * sizeof(int), stream);

    // ---- CSR pass A || layer-1 GEMM (independent; one dispatch) ----
    fused_scatter_gemm<<<nsb + gemmGrid, 256, 0, stream>>>(
        src, dst, ccur, staging, E, nbkt, x, W1, zbuf, N, nsb);

    // ---- CSR pass B (391 light blocks) ----
    bucket_finalize<<<nbkt, 256, 0, stream>>>(staging, ccur, rowse, col, N);

    // ---- layer-1 gather + relu + layer-2 GEMM (one dispatch) ----
    gather_gemm<<<gg2Grid, 512, 0, stream>>>(zbuf, rowse, col, b1, W2, z2buf, N);

    // ---- layer-2 gather + pool ----
    gather_pool<<<gatherGrid, 256, 0, stream>>>(z2buf, rowse, col, b2, sums, batch, N);

    // ---- head ----
    head_kernel<<<G, 64, 0, stream>>>(sums, batch, W3, b3, out, N, NCLS);
}

// Round 4
// 167.198 us; speedup vs baseline: 1.0984x; 1.0984x over previous
//
#include <hip/hip_runtime.h>
#include <hip/hip_bf16.h>
#include <hip/hip_fp16.h>

// GIN via linearity: agg(x)@W == agg(x@W). Per layer: z = X@W (MFMA fp16,
// fp32 accum), then h = relu(z + gather_sum(z) + b) via on-device CSR.
// CSR: single-pass fixed-capacity coarse buckets (dst>>8, CAP slots each),
// packed 4B staging (src:16 | dst&255:16), LDS-local per-bucket finalize.
// r9:  finalize||GEMM1 fused; layer-2 gather pools directly into sums.
// r10: gather1+relu+GEMM2 fused (h rows via LDS tile, no hbuf round-trip).
// r11: REGRESSED (+14us): scatter||GEMM1 w/ CHUNK 1024 + 391 fine bins ->
//      ~7x more device-scope ccur atomics on fewer words; finalize serial.
// r12: revert to r10 structure (best measured, 169.4us); keep only the
//      orthogonal safe piece from r11: col as u16 (halves finalize write
//      + both gathers' index fetch; no contention change).

#define N_FEAT 64
#define CHUNK 4096
#define CAP 6144   // slots per coarse bucket (mean fill 4096, >30 sigma slack)

typedef _Float16 f16;
typedef _Float16 half8 __attribute__((ext_vector_type(8)));
typedef float float4v __attribute__((ext_vector_type(4)));
typedef unsigned short u16;

__device__ inline f16 cvt_f16(float v) { return (f16)v; }
__device__ inline f16 cvt_f16(f16 v) { return v; }

// ---- GEMM body via MFMA: 64 rows/block, 4 waves; wave w = 16-row strip ----
// smem: needs 2*64*72*2 = 18432 bytes
template <typename TIN>
__device__ __forceinline__ void gemm_body(const TIN* __restrict__ X, const float* __restrict__ W,
                                          f16* __restrict__ Z, int nrows, int bidx, char* smemc) {
    f16 (*sX)[72] = (f16 (*)[72])smemc;
    f16 (*sWT)[72] = (f16 (*)[72])(smemc + 64 * 72 * sizeof(f16));
    int t = threadIdx.x;
    int base = bidx * 64;
    for (int idx = t; idx < 4096; idx += 256) {
        int k = idx >> 6, n = idx & 63;
        sWT[n][k] = (f16)W[idx];               // W[k][n] -> sWT[n][k]
    }
    for (int idx = t; idx < 4096; idx += 256) {
        int r = idx >> 6, c = idx & 63;
        int row = base + r;
        sX[r][c] = (row < nrows) ? cvt_f16(X[(size_t)row * 64 + c]) : (f16)0.f;
    }
    __syncthreads();
    int wave = t >> 6;
    int lane = t & 63;
    int quad = lane >> 4;
    int m16 = lane & 15;
    half8 a0 = *(const half8*)&sX[wave * 16 + m16][quad * 8];
    half8 a1 = *(const half8*)&sX[wave * 16 + m16][32 + quad * 8];
    float4v acc[4];
#pragma unroll
    for (int C = 0; C < 4; ++C) {
        half8 b0 = *(const half8*)&sWT[C * 16 + m16][quad * 8];
        half8 b1 = *(const half8*)&sWT[C * 16 + m16][32 + quad * 8];
        float4v d = {0.f, 0.f, 0.f, 0.f};
        d = __builtin_amdgcn_mfma_f32_16x16x32_f16(a0, b0, d, 0, 0, 0);
        d = __builtin_amdgcn_mfma_f32_16x16x32_f16(a1, b1, d, 0, 0, 0);
        acc[C] = d;
    }
#pragma unroll
    for (int reg = 0; reg < 4; ++reg) {
        int row = base + wave * 16 + quad * 4 + reg;
        if (row < nrows) {
#pragma unroll
            for (int C = 0; C < 4; ++C)
                Z[(size_t)row * 64 + C * 16 + m16] = (f16)acc[C][reg];
        }
    }
}

// ---- CSR pass A: coarse-bucket packed edges into fixed-capacity regions ----
// pack = src(16b) | (dst&255)<<16    (requires N <= 65536)
__global__ __launch_bounds__(256) void bucket_scatter(const int* __restrict__ src, const int* __restrict__ dst,
                               int* __restrict__ ccur, int* __restrict__ staging, int E) {
    __shared__ int epack[CHUNK];
    __shared__ int ebkt[CHUNK];
    __shared__ int hist[256];
    __shared__ int base[256];
    int t = threadIdx.x;
    int begin = blockIdx.x * CHUNK;
    int cnt = min(CHUNK, E - begin);
    hist[t] = 0;
    __syncthreads();
    for (int i = t; i < cnt; i += 256) {
        int d = dst[begin + i];
        int s = src[begin + i];
        epack[i] = (s & 0xFFFF) | ((d & 255) << 16);
        ebkt[i] = d >> 8;
        atomicAdd(&hist[d >> 8], 1);
    }
    __syncthreads();
    int h = hist[t];
    if (h > 0) base[t] = atomicAdd(&ccur[t], h);
    hist[t] = 0;
    __syncthreads();
    for (int i = t; i < cnt; i += 256) {
        int b = ebkt[i];
        int off = base[b] + atomicAdd(&hist[b], 1);
        if (off < CAP) staging[(size_t)b * CAP + off] = epack[i];
    }
}

// ---- CSR pass B body: per-bucket hist+scan+scatter fully in LDS ----
// smem: needs (CAP + 768) * 4 = 27648 bytes
__device__ __forceinline__ void finalize_body(const int* __restrict__ staging, const int* __restrict__ ccur,
                                              int2* __restrict__ rowse, u16* __restrict__ col, int N,
                                              int b, char* smemc) {
    int* edges = (int*)smemc;          // CAP
    int* hist = edges + CAP;           // 256
    int* scan = hist + 256;            // 256
    int* cur = scan + 256;             // 256
    int t = threadIdx.x;
    int cnt = min(ccur[b], CAP);
    int sbase = b * CAP;
    hist[t] = 0;
    __syncthreads();
    for (int i = t; i < cnt; i += 256) {
        int e = staging[(size_t)sbase + i];
        edges[i] = e;
        atomicAdd(&hist[(e >> 16) & 255], 1);
    }
    __syncthreads();
    int v = hist[t];
    scan[t] = v;
    __syncthreads();
    for (int off = 1; off < 256; off <<= 1) {
        int u = (t >= off) ? scan[t - off] : 0;
        __syncthreads();
        scan[t] += u;
        __syncthreads();
    }
    int excl = scan[t] - v;
    cur[t] = excl;
    int node = b * 256 + t;
    if (node < N) rowse[node] = make_int2(sbase + excl, sbase + excl + v);
    __syncthreads();
    for (int i = t; i < cnt; i += 256) {
        int e = edges[i];
        int pos = sbase + atomicAdd(&cur[(e >> 16) & 255], 1);
        col[pos] = (u16)(e & 0xFFFF);
    }
}

// ---- fused: finalize (blocks 0..nbf-1) || layer-1 GEMM (blocks nbf..) ----
__global__ __launch_bounds__(256) void fused_finalize_gemm(
        const int* __restrict__ staging, const int* __restrict__ ccur,
        int2* __restrict__ rowse, u16* __restrict__ col, int N,
        const float* __restrict__ X, const float* __restrict__ W,
        f16* __restrict__ Z, int nrows, int nbf) {
    __shared__ __align__(16) char smem[(CAP + 768) * 4];
    if ((int)blockIdx.x < nbf)
        finalize_body(staging, ccur, rowse, col, N, blockIdx.x, smem);
    else
        gemm_body<float>(X, W, Z, nrows, blockIdx.x - nbf, smem);
}

// ---- fused gather1 + relu + layer-2 GEMM ----
// 512 threads = 8 waves; block owns 32 nodes (wave w -> nodes w*4..w*4+3).
// Per node: 8 edge slots (e=lane>>3) x 8 chunks of 16B (c=lane&7), 32 edges
// in flight; shfl-reduce across slots; lanes e==0 write h row to sH[32][72]
// as f16. One barrier, then 8 waves compute the 32x64 z2 tile vs staged W2^T.
__global__ __launch_bounds__(512) void gather_gemm(
        const f16* __restrict__ Z, const int2* __restrict__ rowse,
        const u16* __restrict__ col, const float* __restrict__ bias,
        const float* __restrict__ W2, f16* __restrict__ Z2, int n) {
    __shared__ f16 sH[32][72];
    __shared__ f16 sWT[64][72];
    int t = threadIdx.x;
    for (int idx = t; idx < 4096; idx += 512) {
        int k = idx >> 6, nn = idx & 63;
        sWT[nn][k] = (f16)W2[idx];             // W2[k][n] -> sWT[n][k]
    }
    int w = t >> 6;
    int lane = t & 63;
    int e = lane >> 3, c = lane & 7;
    int base = blockIdx.x * 32;
    const float4v* Z4 = reinterpret_cast<const float4v*>(Z);
    const float4* B4 = reinterpret_cast<const float4*>(bias);
#pragma unroll
    for (int q = 0; q < 4; ++q) {
        int node = base + w * 4 + q;
        bool valid = node < n;
        int lo = 0, hi = 0;
        if (valid) { int2 se = rowse[node]; lo = se.x; hi = se.y; }
        float acc[8] = {0.f, 0.f, 0.f, 0.f, 0.f, 0.f, 0.f, 0.f};
        int idx4[4];
#pragma unroll
        for (int i = 0; i < 4; ++i) {
            int j = lo + e + i * 8;
            idx4[i] = (j < hi) ? (int)col[j] : -1;
        }
#pragma unroll
        for (int i = 0; i < 4; ++i) {
            if (idx4[i] >= 0) {
                float4v r = Z4[(size_t)idx4[i] * 8 + c];
                half8 hv = *(half8*)&r;
#pragma unroll
                for (int k = 0; k < 8; ++k) acc[k] += (float)hv[k];
            }
        }
        for (int j = lo + 32 + e; j < hi; j += 8) {   // rare tail (deg > 32)
            float4v r = Z4[(size_t)(int)col[j] * 8 + c];
            half8 hv = *(half8*)&r;
#pragma unroll
            for (int k = 0; k < 8; ++k) acc[k] += (float)hv[k];
        }
#pragma unroll
        for (int k = 0; k < 8; ++k) {
            acc[k] += __shfl_xor(acc[k], 8);
            acc[k] += __shfl_xor(acc[k], 16);
            acc[k] += __shfl_xor(acc[k], 32);
        }
        if (e == 0) {                          // lane == c here
            half8 o;
            if (valid) {
                float4v sr = Z4[(size_t)node * 8 + c];
                half8 sv = *(half8*)&sr;
                float4 b0 = B4[c * 2];
                float4 b1 = B4[c * 2 + 1];
                float bb[8] = {b0.x, b0.y, b0.z, b0.w, b1.x, b1.y, b1.z, b1.w};
#pragma unroll
                for (int k = 0; k < 8; ++k)
                    o[k] = (f16)fmaxf((float)sv[k] + acc[k] + bb[k], 0.f);
            } else {
#pragma unroll
                for (int k = 0; k < 8; ++k) o[k] = (f16)0.f;
            }
            *(half8*)&sH[w * 4 + q][c * 8] = o;
        }
    }
    __syncthreads();
    // ---- 32x64 MFMA: wave w -> output tile (mrow = (w>>2)*16, ncol = (w&3)*16)
    int quad = lane >> 4;
    int m16 = lane & 15;
    int mrow = (w >> 2) * 16;
    int ncol = (w & 3) * 16;
    half8 a0 = *(const half8*)&sH[mrow + m16][quad * 8];
    half8 a1 = *(const half8*)&sH[mrow + m16][32 + quad * 8];
    half8 b0 = *(const half8*)&sWT[ncol + m16][quad * 8];
    half8 b1 = *(const half8*)&sWT[ncol + m16][32 + quad * 8];
    float4v d = {0.f, 0.f, 0.f, 0.f};
    d = __builtin_amdgcn_mfma_f32_16x16x32_f16(a0, b0, d, 0, 0, 0);
    d = __builtin_amdgcn_mfma_f32_16x16x32_f16(a1, b1, d, 0, 0, 0);
#pragma unroll
    for (int reg = 0; reg < 4; ++reg) {
        int row = base + mrow + quad * 4 + reg;
        if (row < n)
            Z2[(size_t)row * 64 + ncol + m16] = (f16)d[reg];
    }
}

// ---- gather2 + bias + relu + pool; 1 wave/node ----
// Block-local LDS combine of the 4 waves' h rows, atomicAdd per distinct
// graph (batch sorted -> usually one graph per block -> ~64 atomics/block).
__global__ __launch_bounds__(256) void gather_pool(
        const f16* __restrict__ Z, const int2* __restrict__ rowse,
        const u16* __restrict__ col, const float* __restrict__ bias,
        float* __restrict__ sums, const int* __restrict__ batch, int n) {
    __shared__ float sh[4][64];
    __shared__ int gid[4];
    int w = threadIdx.x >> 6;
    int node = (int)(blockIdx.x * 4 + w);
    int lane = threadIdx.x & 63;
    int e = lane >> 3, c = lane & 7;
    bool valid = node < n;
    int lo = 0, hi = 0;
    if (valid) { int2 se = rowse[node]; lo = se.x; hi = se.y; }
    const float4v* Z4 = reinterpret_cast<const float4v*>(Z);
    float acc[8] = {0.f, 0.f, 0.f, 0.f, 0.f, 0.f, 0.f, 0.f};
    int idx[4];
#pragma unroll
    for (int i = 0; i < 4; ++i) {
        int j = lo + e + i * 8;
        idx[i] = (j < hi) ? (int)col[j] : -1;
    }
#pragma unroll
    for (int i = 0; i < 4; ++i) {
        if (idx[i] >= 0) {
            float4v r = Z4[(size_t)idx[i] * 8 + c];
            half8 hv = *(half8*)&r;
#pragma unroll
            for (int k = 0; k < 8; ++k) acc[k] += (float)hv[k];
        }
    }
    for (int j = lo + 32 + e; j < hi; j += 8) {   // rare tail (deg > 32)
        float4v r = Z4[(size_t)(int)col[j] * 8 + c];
        half8 hv = *(half8*)&r;
#pragma unroll
        for (int k = 0; k < 8; ++k) acc[k] += (float)hv[k];
    }
#pragma unroll
    for (int k = 0; k < 8; ++k) {
        acc[k] += __shfl_xor(acc[k], 8);
        acc[k] += __shfl_xor(acc[k], 16);
        acc[k] += __shfl_xor(acc[k], 32);
    }
    if (lane == 0) gid[w] = valid ? batch[node] : -1;
    if (valid && e == 0) {
        float4v sr = Z4[(size_t)node * 8 + c];
        half8 sv = *(half8*)&sr;
        const float4* B4 = reinterpret_cast<const float4*>(bias);
        float4 b0 = B4[c * 2];
        float4 b1 = B4[c * 2 + 1];
        float bb[8] = {b0.x, b0.y, b0.z, b0.w, b1.x, b1.y, b1.z, b1.w};
#pragma unroll
        for (int k = 0; k < 8; ++k)
            sh[w][c * 8 + k] = fmaxf((float)sv[k] + acc[k] + bb[k], 0.f);
    }
    __syncthreads();
    if (w == 0) {
        int cg = gid[0];
        float run = 0.f;
#pragma unroll
        for (int q = 0; q < 4; ++q) {
            int g = gid[q];
            if (g < 0) break;
            if (g != cg) {
                atomicAdd(&sums[cg * 64 + lane], run);
                run = 0.f;
                cg = g;
            }
            run += sh[q][lane];
        }
        if (cg >= 0) atomicAdd(&sums[cg * 64 + lane], run);
    }
}

// ---- tiny head: out[g] = (sums[g]/cnt[g]) @ W3 + b3 ----
__global__ __launch_bounds__(64) void head_kernel(
        const float* __restrict__ sums, const int* __restrict__ batch,
        const float* __restrict__ W3, const float* __restrict__ b3,
        float* __restrict__ out, int n, int ncls) {
    int g = blockIdx.x;
    __shared__ float row[64];
    __shared__ int bnd[2];
    int t = threadIdx.x;
    if (t < 2) {
        int target = g + t;
        int lo = 0, hi = n;
        while (lo < hi) { int m = (lo + hi) >> 1; if (batch[m] < target) lo = m + 1; else hi = m; }
        bnd[t] = lo;
    }
    __syncthreads();
    float cnt = fmaxf((float)(bnd[1] - bnd[0]), 1.0f);
    row[t] = sums[g * 64 + t] / cnt;
    __syncthreads();
    if (t < ncls) {
        float o = b3[t];
#pragma unroll
        for (int k = 0; k < 64; ++k) o += row[k] * W3[k * ncls + t];
        out[g * ncls + t] = o;
    }
}

extern "C" void kernel_launch(void* const* d_in, const int* in_sizes, int n_in,
                              void* d_out, int out_size, void* d_ws, size_t ws_size,
                              hipStream_t stream) {
    const float* x     = (const float*)d_in[0];
    const int*   ei    = (const int*)d_in[1];   // [2, E]
    const int*   batch = (const int*)d_in[2];
    const float* W1    = (const float*)d_in[3];
    const float* b1    = (const float*)d_in[4];
    const float* W2    = (const float*)d_in[5];
    const float* b2    = (const float*)d_in[6];
    const float* W3    = (const float*)d_in[7];
    const float* b3    = (const float*)d_in[8];
    float* out = (float*)d_out;

    const int N = in_sizes[0] / N_FEAT;       // 50000
    const int E = in_sizes[1] / 2;            // 800000
    const int NCLS = 10;
    const int G = out_size / NCLS;            // 500
    const int* src = ei;
    const int* dst = ei + E;
    const int nb = (N + 255) / 256;           // 196 coarse buckets

    // workspace layout (all offsets kept 16B-aligned)
    int*   staging = (int*)d_ws;                              // nb*CAP packed
    int2*  rowse   = (int2*)(staging + (size_t)nb * CAP);     // N
    u16*   col     = (u16*)(rowse + N);                       // nb*CAP (2B each)
    size_t colInts = ((size_t)nb * CAP * 2 + 15) / 16 * 4;    // in ints, 16B pad
    int*   ccur    = (int*)(rowse + N) + colInts;             // 256
    float* sums    = (float*)(ccur + 256);                    // G*64 (pool acc)
    f16*   zbuf    = (f16*)(sums + (size_t)G * 64);           // N*64  (z1)
    f16*   z2buf   = zbuf + (size_t)N * 64;                   // N*64  (z2)

    const int gemmGrid = (N + 63) / 64;
    const int gg2Grid  = (N + 31) / 32;
    const int gatherGrid = (N + 3) / 4;
    const int scatGrid = (E + CHUNK - 1) / CHUNK;

    // ---- CSR pass A + zero (ccur + sums contiguous) ----
    hipMemsetAsync(ccur, 0, (256 + (size_t)G * 64) * sizeof(int), stream);
    bucket_scatter<<<scatGrid, 256, 0, stream>>>(src, dst, ccur, staging, E);

    // ---- CSR pass B || layer-1 GEMM (independent; one dispatch) ----
    fused_finalize_gemm<<<nb + gemmGrid, 256, 0, stream>>>(
        staging, ccur, rowse, col, N, x, W1, zbuf, N, nb);

    // ---- layer-1 gather + relu + layer-2 GEMM (one dispatch) ----
    gather_gemm<<<gg2Grid, 512, 0, stream>>>(zbuf, rowse, col, b1, W2, z2buf, N);

    // ---- layer-2 gather + pool ----
    gather_pool<<<gatherGrid, 256, 0, stream>>>(z2buf, rowse, col, b2, sums, batch, N);

    // ---- head ----
    head_kernel<<<G, 64, 0, stream>>>(sums, batch, W3, b3, out, N, NCLS);
}